// Round 11
// baseline (65.693 us; speedup 1.0000x reference)
//
#include <hip/hip_runtime.h>

#define HH 192
#define WW 192
#define BB 2
#define NC 6
#define FSZ 11
#define PAD 5
#define TW 96              // tile cols
#define TH 3               // tile rows  -> 288 px = exactly 1 block per CU
#define SWD 107            // staged cols (96 + 10 + 1 guard)
#define SHT 14             // staged rows (3 + 10 + 1 phantom)
#define LA 107             // LDS row stride (odd)
#define HW (HH*WW)
#define BT 768             // 12 waves

// bf16 pack/unpack (round-half-up)
__device__ __forceinline__ unsigned pkbf(float a, float b) {
    unsigned ua = (__float_as_uint(a) + 0x8000u) >> 16;
    unsigned ub = (__float_as_uint(b) + 0x8000u) & 0xffff0000u;
    return ua | ub;
}
__device__ __forceinline__ float lo16(unsigned u){ return __uint_as_float(u << 16); }
__device__ __forceinline__ float hi16(unsigned u){ return __uint_as_float(u & 0xffff0000u); }

// One mean-field iteration. 96x3 tile, grid 2x64x2 = 256 blocks = 1/CU exact.
// 12 waves: 4 per tile-row; wave owns 24 px (8 triples). Lane = (triple t,
// rb, half): rows {rb,rb+4,rb+8} (rb=3: phantom row 11 zero-coeff), cols
// j in [6*half, 6*half+jcnt). P=3 sliding window. Reduction: 3x shfl_xor
// in-register; lanes l%8==0 do the epilogue for their 3 px. One barrier total.
// Slabs: A = px-major uint4 (q01,q23,q45,f01 bf16x2, f prescaled by
// iab*sqrt(0.5)); f2 = f32 slab (prescaled), written by FIRST.
template<bool FIRST, bool LAST>
__global__ __launch_bounds__(BT, 3)
void crf_it(const float* __restrict__ xpl, const uint4* __restrict__ Ain,
            const float* __restrict__ f2in, const float* __restrict__ feats,
            const float* __restrict__ spac, const float* __restrict__ swp,
            const float* __restrict__ awp, const float* __restrict__ isbp,
            const float* __restrict__ iabp,
            uint4* __restrict__ Aout, float* __restrict__ f2out,
            float* __restrict__ outp)
{
    __shared__ uint4 A[SHT][LA];     // ~24 KB
    __shared__ float F2[SHT][LA];    // ~6 KB
    __shared__ float sfw[FSZ*FSZ];
    __shared__ float sfa[FSZ*FSZ];

    const int tid = threadIdx.x;
    const int b  = blockIdx.z;
    const int w0 = blockIdx.x * TW;
    const int h0 = blockIdx.y * TH;

    const float sw  = swp[0], aw = awp[0], isb = isbp[0], iab = iabp[0];
    const float s0  = spac[b*2], s1 = spac[b*2+1];
    const float sfac = iab * 0.70710678f;

    if (tid < FSZ*FSZ) {
        const int fi = tid / FSZ, fj = tid - (tid/FSZ)*FSZ;
        const float ri = (float)(fi-PAD) * s0 * isb;
        const float rj = (float)(fj-PAD) * s1 * isb;
        float sf = __expf(-0.5f*(ri*ri + rj*rj));
        if (fi == PAD && fj == PAD) sf = 0.f;
        sfw[tid] = sf * sw;
        sfa[tid] = sf * aw;
    }

    // ---- stage 14 x 107 (zeros outside image) ----
    for (int idx = tid; idx < SHT*SWD; idx += BT) {
        const int sr = idx / SWD, sc = idx - (idx/SWD)*SWD;
        const int gh = h0 + sr - PAD, gw = w0 + sc - PAD;
        uint4 av = make_uint4(0u,0u,0u,0u);
        float f2v = 0.f;
        if (gh >= 0 && gh < HH && gw >= 0 && gw < WW) {
            if (FIRST) {
                const int off = gh*WW + gw;
                const float* xb = xpl + (size_t)b*NC*HW + off;
                const float v0 = xb[0], v1 = xb[HW], v2 = xb[2*HW];
                const float v3 = xb[3*HW], v4 = xb[4*HW], v5 = xb[5*HW];
                float m = fmaxf(fmaxf(fmaxf(v0,v1),fmaxf(v2,v3)),fmaxf(v4,v5));
                float q0=__expf(v0-m), q1=__expf(v1-m), q2=__expf(v2-m);
                float q3=__expf(v3-m), q4=__expf(v4-m), q5=__expf(v5-m);
                const float rs = 1.0f/(q0+q1+q2+q3+q4+q5);
                const float* fb = feats + (size_t)b*3*HW + off;
                const float g0 = fb[0]*sfac, g1 = fb[HW]*sfac;
                f2v = fb[2*HW]*sfac;
                av = make_uint4(pkbf(q0*rs,q1*rs), pkbf(q2*rs,q3*rs),
                                pkbf(q4*rs,q5*rs), pkbf(g0,g1));
            } else {
                const size_t p = (size_t)(b*HH + gh)*WW + gw;
                av  = Ain[p];
                f2v = f2in[p];
            }
        }
        A[sr][sc]  = av;
        F2[sr][sc] = f2v;
    }
    __syncthreads();

    // ---- roles ----
    const int w    = tid >> 6;        // wave 0..11
    const int l    = tid & 63;
    const int t3   = l >> 3;          // triple 0..7
    const int rb   = (l >> 1) & 3;    // row band
    const int hf   = l & 1;           // col half
    const int prow = w >> 2;          // tile row 0..2
    const int cb   = (w & 3)*24 + t3*3;   // first px col (0..93)
    const int jb   = hf*6;
    const int jcnt = hf ? 5 : 6;

    // center features (prescaled) for the 3 px
    float cf0[3], cf1[3], cf2[3];
    #pragma unroll
    for (int k = 0; k < 3; ++k) {
        const uint4 cav = A[prow+PAD][cb+k+PAD];
        cf0[k] = lo16(cav.w);
        cf1[k] = hi16(cav.w);
        cf2[k] = F2[prow+PAD][cb+k+PAD];
    }

    float ms[3][NC];
    #pragma unroll
    for (int k = 0; k < 3; ++k)
        #pragma unroll
        for (int c = 0; c < NC; ++c) ms[k][c] = 0.f;

    // ---- main: 3 row-iterations x 8-step sliding window ----
    #pragma unroll
    for (int m = 0; m < 3; ++m) {
        const int i = rb + 4*m;               // filter row (11 = phantom)
        const bool vrow = (i < FSZ);
        float srwR[6], sraR[6];
        #pragma unroll
        for (int d = 0; d < 6; ++d) {
            const bool v = vrow && (d < jcnt);
            srwR[d] = v ? sfw[i*FSZ + jb + d] : 0.f;
            sraR[d] = v ? sfa[i*FSZ + jb + d] : 0.f;
        }
        const uint4* Ar = &A[prow + i][cb + jb];
        const float* Fr = &F2[prow + i][cb + jb];
        #pragma unroll
        for (int a = 0; a < 8; ++a) {
            const uint4 av = Ar[a];
            const float g2 = Fr[a];
            const float q0 = lo16(av.x), q1 = hi16(av.x);
            const float q2 = lo16(av.y), q3 = hi16(av.y);
            const float q4 = lo16(av.z), q5 = hi16(av.z);
            const float g0 = lo16(av.w), g1 = hi16(av.w);
            #pragma unroll
            for (int k = 0; k < 3; ++k) {
                const int d = a - k;
                if (0 <= d && d < 6) {
                    const float d0 = cf0[k]-g0, d1 = cf1[k]-g1, d2 = cf2[k]-g2;
                    const float t  = fmaf(d2,d2, fmaf(d1,d1, d0*d0));
                    const float af = __expf(-t);
                    const float tf = fmaf(af, sraR[d], srwR[d]);
                    ms[k][0] = fmaf(tf,q0,ms[k][0]);
                    ms[k][1] = fmaf(tf,q1,ms[k][1]);
                    ms[k][2] = fmaf(tf,q2,ms[k][2]);
                    ms[k][3] = fmaf(tf,q3,ms[k][3]);
                    ms[k][4] = fmaf(tf,q4,ms[k][4]);
                    ms[k][5] = fmaf(tf,q5,ms[k][5]);
                }
            }
        }
    }

    // ---- in-register reduction over (half, rb): xor 1, 2, 4 ----
    #pragma unroll
    for (int k = 0; k < 3; ++k)
        #pragma unroll
        for (int c = 0; c < NC; ++c) {
            float v = ms[k][c];
            v += __shfl_xor(v, 1);
            v += __shfl_xor(v, 2);
            v += __shfl_xor(v, 4);
            ms[k][c] = v;
        }

    // ---- epilogue: lanes l%8==0 own 3 px each (no barrier needed) ----
    if ((l & 7) == 0) {
        #pragma unroll
        for (int k = 0; k < 3; ++k) {
            const int oh = h0 + prow, ow = w0 + cb + k;
            const size_t pb = (size_t)b*NC*HW + (size_t)oh*WW + ow;
            float xn[NC];
            #pragma unroll
            for (int c = 0; c < NC; ++c) xn[c] = ms[k][c] + xpl[pb + (size_t)c*HW];

            float m = xn[0];
            #pragma unroll
            for (int c = 1; c < NC; ++c) m = fmaxf(m, xn[c]);

            if (LAST) {
                float s = 0.f;
                #pragma unroll
                for (int c = 0; c < NC; ++c) s += __expf(xn[c]-m);
                const float lg = m + __logf(s);
                #pragma unroll
                for (int c = 0; c < NC; ++c) outp[pb + (size_t)c*HW] = xn[c] - lg;
            } else {
                float e[NC], s = 0.f;
                #pragma unroll
                for (int c = 0; c < NC; ++c) { e[c] = __expf(xn[c]-m); s += e[c]; }
                const float rs = 1.0f / s;
                const size_t p = (size_t)(b*HH + oh)*WW + ow;
                Aout[p] = make_uint4(pkbf(e[0]*rs,e[1]*rs), pkbf(e[2]*rs,e[3]*rs),
                                     pkbf(e[4]*rs,e[5]*rs), pkbf(cf0[k],cf1[k]));
                if (FIRST) f2out[p] = cf2[k];
            }
        }
    }
}

extern "C" void kernel_launch(void* const* d_in, const int* in_sizes, int n_in,
                              void* d_out, int out_size, void* d_ws, size_t ws_size,
                              hipStream_t stream)
{
    const float* x    = (const float*)d_in[0];
    const float* fts  = (const float*)d_in[1];
    const float* spc  = (const float*)d_in[2];
    const float* swp  = (const float*)d_in[3];
    const float* awp  = (const float*)d_in[4];
    const float* isbp = (const float*)d_in[5];
    const float* iabp = (const float*)d_in[6];
    float* out = (float*)d_out;

    uint4* A0  = (uint4*)d_ws;                     // 1.18 MB (q+f01, px-major)
    uint4* A1  = A0 + (size_t)BB*HW;               // 1.18 MB
    float* f2s = (float*)(A1 + (size_t)BB*HW);     // 0.29 MB

    dim3 grid(WW/TW, HH/TH, BB);   // 2 x 64 x 2 = 256 blocks = 1 per CU
    dim3 blk(BT);                  // 768 threads = 12 waves

    crf_it<true ,false><<<grid, blk, 0, stream>>>(x, A1, f2s, fts, spc, swp, awp, isbp, iabp, A0, f2s, out);
    crf_it<false,false><<<grid, blk, 0, stream>>>(x, A0, f2s, fts, spc, swp, awp, isbp, iabp, A1, f2s, out);
    crf_it<false,false><<<grid, blk, 0, stream>>>(x, A1, f2s, fts, spc, swp, awp, isbp, iabp, A0, f2s, out);
    crf_it<false,false><<<grid, blk, 0, stream>>>(x, A0, f2s, fts, spc, swp, awp, isbp, iabp, A1, f2s, out);
    crf_it<false,true ><<<grid, blk, 0, stream>>>(x, A1, f2s, fts, spc, swp, awp, isbp, iabp, A0, f2s, out);
}